// Round 2
// baseline (473.114 us; speedup 1.0000x reference)
//
#include <hip/hip_runtime.h>
#include <hip/hip_cooperative_groups.h>
#include <hip/hip_bf16.h>

namespace cg = cooperative_groups;

#define B_ 8
#define S_ 2048
#define E_ 1024
#define D_ 64
#define VT_STRIDE 2112   // 2048 + 64: breaks 4KB channel camping

typedef short short8 __attribute__((ext_vector_type(8)));
typedef short short4v __attribute__((ext_vector_type(4)));
typedef float floatx4 __attribute__((ext_vector_type(4)));

static __device__ __forceinline__ short bf16_bits(float f) {
    __hip_bfloat16 h = __float2bfloat16(f);
    return *reinterpret_cast<short*>(&h);
}
static __device__ __forceinline__ float bits_to_f(short s) {
    __hip_bfloat16 h = *reinterpret_cast<__hip_bfloat16*>(&s);
    return __bfloat162float(h);
}
static __device__ __forceinline__ void split8(const float* __restrict__ p,
                                              short8& hi, short8& lo) {
    #pragma unroll
    for (int j = 0; j < 8; j++) {
        float f = p[j];
        short h = bf16_bits(f);
        hi[j] = h;
        lo[j] = bf16_bits(f - bits_to_f(h));
    }
}
static __device__ __forceinline__ void split8v(const float v[8],
                                               short8& hi, short8& lo) {
    #pragma unroll
    for (int j = 0; j < 8; j++) {
        float f = v[j];
        short h = bf16_bits(f);
        hi[j] = h;
        lo[j] = bf16_bits(f - bits_to_f(h));
    }
}
static __device__ __forceinline__ void dma16(const void* src, void* lds_dst) {
    __builtin_amdgcn_global_load_lds(
        (const __attribute__((address_space(1))) unsigned int*)src,
        (__attribute__((address_space(3))) unsigned int*)lds_dst, 16, 0, 0);
}

// =================== FUSED cooperative kernel ===================
// Phase A (prep): blocks 0..47 W-pack, 48..79 maskf, 80..87 compaction.
// grid.sync()
// Phase B (qkv): all 512 blocks, 512 threads (verbatim round-1 body).
// grid.sync()
// Phase C (attn): waves 0..3 only (waves 4..7 exit; legal early-exit).
union alignas(16) FusedLds {
    unsigned int red[512];                                           // prep: 2KB
    struct { float xs[2][2][1024]; short8 wt[2][1536]; } qk;         // 64KB
    struct {
        union {
            struct { short8 kts[4][512]; short8 vts[4][512]; } st;   // 64KB
            struct { float Osh[4][16][65]; float msh[4][16], lsh[4][16]; } mg;
        } u;
        short PlT[4][16][72];                                        // 9.2KB
    } at;                                                            // 73.0KB
};

__global__ __launch_bounds__(512, 4) void fused_kernel(
    const float* __restrict__ x,
    const float* __restrict__ Wq, const float* __restrict__ bq,
    const float* __restrict__ Wk, const float* __restrict__ bk,
    const float* __restrict__ Wv, const float* __restrict__ bv,
    const void* __restrict__ mask_raw,
    short8* __restrict__ Wpk8,
    short* __restrict__ Qhi, short* __restrict__ Qlo,
    short* __restrict__ Khi, short* __restrict__ Vt,
    float* __restrict__ maskf, float* __restrict__ maskc,
    short* __restrict__ cidx, int* __restrict__ nrounds,
    float* __restrict__ out)
{
    __shared__ FusedLds L;
    cg::grid_group grid = cg::this_grid();
    const int tid = threadIdx.x;   // 0..511
    const int bx  = blockIdx.x;    // 0..511

    // ---------------- phase A: prep ----------------
    if (bx < 48) {
        const int t = bx * 512 + tid;             // 0..24575
        const int l16  = t & 15;
        const int quad = (t >> 4) & 3;
        const int nb   = (t >> 6) & 3;
        const int m    = (t >> 8) % 3;
        const int e0c  = (t >> 8) / 3;            // 0..31
        const float* W = (m == 0) ? Wq : ((m == 1) ? Wk : Wv);
        short8 hi, lo;
        split8(W + (size_t)(nb * 16 + l16) * E_ + e0c * 32 + quad * 8, hi, lo);
        Wpk8[(size_t)e0c * 768 + m * 256 + nb * 64 + quad * 16 + l16] = hi;
    } else if (bx < 88) {
        const unsigned int* w = (const unsigned int*)mask_raw;
        unsigned int local = 0;
        for (int i = tid; i < 4096; i += 512) local |= w[i];
        L.red[tid] = local;
        __syncthreads();
        for (int s = 256; s > 0; s >>= 1) {
            if (tid < s) L.red[tid] |= L.red[tid + s];
            __syncthreads();
        }
        const unsigned int ov = L.red[0];
        const bool is_u8 = (ov > 1u) && ((ov >> 24) <= 1u);
        if (bx < 80) {
            const int i = (bx - 48) * 512 + tid;  // 0..16383
            int v;
            if (ov == 0u)      v = 0;
            else if (is_u8)    v = (int)((const unsigned char*)mask_raw)[i];
            else               v = (w[i] != 0u);
            maskf[i] = v ? -1e30f : 0.0f;
        } else {
            const int b = bx - 80;                // batch 0..7
            int um[4];
            #pragma unroll
            for (int j = 0; j < 4; j++) {
                const int i = b * 2048 + tid * 4 + j;
                int v;
                if (ov == 0u)      v = 0;
                else if (is_u8)    v = (int)((const unsigned char*)mask_raw)[i];
                else               v = (w[i] != 0u);
                um[j] = v ? 0 : 1;                // 1 = keep (unmasked)
            }
            const int cnt = um[0] + um[1] + um[2] + um[3];
            __syncthreads();                      // done reading red[0]
            L.red[tid] = (unsigned int)cnt;
            __syncthreads();
            for (int off = 1; off < 512; off <<= 1) {   // inclusive scan
                unsigned int a = 0;
                if (tid >= off) a = L.red[tid - off];
                __syncthreads();
                L.red[tid] += a;
                __syncthreads();
            }
            const int total = (int)L.red[511];    // nk for this batch
            int pos = (int)L.red[tid] - cnt;      // exclusive base
            #pragma unroll
            for (int j = 0; j < 4; j++) {
                cidx[b * 2048 + tid * 4 + j] = (short)(um[j] ? pos : -1);
                pos += um[j];
            }
            int nr = (total + 127) >> 7;
            if (nr == 0) nr = 1;
            if (tid == 0) nrounds[b] = nr;
            for (int k = tid; k < 2048; k += 512)
                maskc[b * 2048 + k] = (k < total) ? 0.0f : -1e30f;
            const int padn = (nr * 128 - total) * 64;
            for (int idx = tid; idx < padn; idx += 512) {
                const int p = total + (idx >> 6);
                const int d = idx & 63;
                Khi[((size_t)b * 2048 + p) * 64 + d] = 0;
                Vt[((size_t)(b * 64 + d)) * VT_STRIDE + p] = 0;
            }
        }
    }

    __threadfence();
    grid.sync();

    // ---------------- phase B: qkv (verbatim) ----------------
    {
        const int wave = tid >> 6;
        const int nb   = wave & 3;
        const int rt   = wave >> 2;
        const int lane = tid & 63;
        const int l16  = lane & 15;
        const int quad = lane >> 4;
        const int row0 = bx * 32;

        const int xr_  = (tid >> 3) & 31;
        const int xc_  = tid >> 8;
        const float* xsrc = x + (size_t)(row0 + xr_) * E_ + xc_ * 32 +
                            (((tid & 7) ^ (xr_ & 7)) * 4);
        const int xdst = xc_ * 1024 + xr_ * 32 + (tid & 7) * 4;

        floatx4 acc[3];
        #pragma unroll
        for (int m = 0; m < 3; m++) acc[m] = (floatx4){0.f,0.f,0.f,0.f};

        #pragma unroll
        for (int i = 0; i < 3; i++)
            dma16(Wpk8 + (size_t)i * 512 + tid, &L.qk.wt[0][i * 512 + tid]);
        dma16(xsrc, &L.qk.xs[0][0][0] + xdst);

        int buf = 0;
        for (int R = 0; R < 16; ++R) {
            __syncthreads();   // drains this round's DMA
            if (R + 1 < 16) {
                #pragma unroll
                for (int i = 0; i < 3; i++)
                    dma16(Wpk8 + (size_t)(R + 1) * 1536 + i * 512 + tid,
                          &L.qk.wt[buf ^ 1][i * 512 + tid]);
                dma16(xsrc + (R + 1) * 64, &L.qk.xs[buf ^ 1][0][0] + xdst);
            }

            #pragma unroll
            for (int c = 0; c < 2; c++) {
                const int rr = rt * 16 + l16;
                const int rx = rr & 7;
                const float* xrp = &L.qk.xs[buf][c][rr * 32];
                float4 a0 = *reinterpret_cast<const float4*>(xrp + (((2 * quad)     ^ rx) * 4));
                float4 a1 = *reinterpret_cast<const float4*>(xrp + (((2 * quad + 1) ^ rx) * 4));
                float av[8] = {a0.x, a0.y, a0.z, a0.w, a1.x, a1.y, a1.z, a1.w};
                short8 ah, al;
                split8v(av, ah, al);
                #pragma unroll
                for (int m = 0; m < 3; m++) {
                    short8 wh = L.qk.wt[buf][c * 768 + m * 256 + nb * 64 + lane];
                    acc[m] = __builtin_amdgcn_mfma_f32_16x16x32_bf16(al, wh, acc[m], 0, 0, 0);
                    acc[m] = __builtin_amdgcn_mfma_f32_16x16x32_bf16(ah, wh, acc[m], 0, 0, 0);
                }
            }
            buf ^= 1;
        }

        const int d = nb * 16 + l16;
        const float bqv = bq[d];
        const float bkv = bk[d];
        const float bvv = bv[d];
        const int bch = row0 >> 11;
        const int rowbase = row0 + rt * 16 + quad * 4;
        #pragma unroll
        for (int r = 0; r < 4; r++) {
            const size_t row = (size_t)(rowbase + r);
            const float q = (acc[0][r] + bqv) * 0.125f;
            const short qhv = bf16_bits(q);
            Qhi[row * 64 + d] = qhv;
            Qlo[row * 64 + d] = bf16_bits(q - bits_to_f(qhv));
            if (maskf[row] == 0.0f) {   // unmasked key -> compacted scatter
                const int cpos = (int)cidx[row];
                Khi[((size_t)(bch << 11) + cpos) * 64 + d] = bf16_bits(acc[1][r] + bkv);
                Vt[((size_t)(bch * 64 + d)) * VT_STRIDE + cpos] = bf16_bits(acc[2][r] + bvv);
            }
        }
    }

    __threadfence();
    grid.sync();

    // ---------------- phase C: attn (waves 0..3 only) ----------------
    if (tid >= 256) return;
    {
        const int t    = tid;
        const int wave = t >> 6;
        const int qsub = wave & 1;
        const int par  = wave >> 1;
        const int lane = t & 63;
        const int l16  = lane & 15;
        const int quad = lane >> 4;
        const int b    = bx >> 6;
        const int qt   = bx & 63;
        const int NR   = nrounds[b];
        const size_t qbase  = (size_t)b * S_ + qt * 32 + qsub * 16;
        const size_t kplane = (size_t)b * S_;
        const short* Vb = Vt + (size_t)b * 64 * VT_STRIDE;

        short8 qh[2], ql[2];
        #pragma unroll
        for (int dc = 0; dc < 2; dc++) {
            qh[dc] = *reinterpret_cast<const short8*>(Qhi + (qbase + l16) * 64 + dc * 32 + quad * 8);
            ql[dc] = *reinterpret_cast<const short8*>(Qlo + (qbase + l16) * 64 + dc * 32 + quad * 8);
        }

        float m = -1e30f, l = 0.f;
        floatx4 O[4];
        #pragma unroll
        for (int ob = 0; ob < 4; ob++) O[ob] = (floatx4){0.f,0.f,0.f,0.f};

        #pragma unroll
        for (int p = 0; p < 2; p++) {
            #pragma unroll
            for (int i = 0; i < 2; i++) {
                const int c = i * 256 + t;
                const int r = c >> 3, cs = c & 7;
                dma16(Khi + (kplane + p * 64 + r) * 64 + ((cs ^ (r & 7)) * 8),
                      &L.at.u.st.kts[p][c]);
                dma16(Vb + (size_t)r * VT_STRIDE + p * 64 + ((cs ^ (r & 7)) * 8),
                      &L.at.u.st.vts[p][c]);
            }
        }
        float4 mk4[4];
        #pragma unroll
        for (int kb = 0; kb < 4; kb++)
            mk4[kb] = *reinterpret_cast<const float4*>(
                maskc + kplane + par * 64 + kb * 16 + quad * 4);

        for (int R = 0; R < NR; ++R) {
            __syncthreads();
            const int set = R & 1;
            if (R + 1 < NR) {
                const int nset = set ^ 1;
                const int kt2 = (R + 1) * 128;
                #pragma unroll
                for (int p = 0; p < 2; p++) {
                    #pragma unroll
                    for (int i = 0; i < 2; i++) {
                        const int c = i * 256 + t;
                        const int r = c >> 3, cs = c & 7;
                        dma16(Khi + (kplane + kt2 + p * 64 + r) * 64 + ((cs ^ (r & 7)) * 8),
                              &L.at.u.st.kts[nset * 2 + p][c]);
                        dma16(Vb + (size_t)r * VT_STRIDE + kt2 + p * 64 + ((cs ^ (r & 7)) * 8),
                              &L.at.u.st.vts[nset * 2 + p][c]);
                    }
                }
            }
            const int buf = set * 2 + par;

            floatx4 sc[4];
            #pragma unroll
            for (int kb = 0; kb < 4; kb++) {
                floatx4 a = (floatx4){0.f,0.f,0.f,0.f};
                #pragma unroll
                for (int kc = 0; kc < 2; kc++) {
                    const int key = kb * 16 + l16;
                    short8 kf = L.at.u.st.kts[buf][key * 8 + ((kc * 4 + quad) ^ (key & 7))];
                    a = __builtin_amdgcn_mfma_f32_16x16x32_bf16(kf, qh[kc], a, 0, 0, 0);
                    a = __builtin_amdgcn_mfma_f32_16x16x32_bf16(kf, ql[kc], a, 0, 0, 0);
                }
                sc[kb] = a;
            }
            #pragma unroll
            for (int kb = 0; kb < 4; kb++) {
                const float* mkp = reinterpret_cast<const float*>(&mk4[kb]);
                #pragma unroll
                for (int r = 0; r < 4; r++) sc[kb][r] += mkp[r];
            }

            if (R + 1 < NR) {
                const int ktn = (R + 1) * 128 + par * 64;
                #pragma unroll
                for (int kb = 0; kb < 4; kb++)
                    mk4[kb] = *reinterpret_cast<const float4*>(
                        maskc + kplane + ktn + kb * 16 + quad * 4);
            }

            float mx = -1e30f;
            #pragma unroll
            for (int kb = 0; kb < 4; kb++)
                #pragma unroll
                for (int r = 0; r < 4; r++) mx = fmaxf(mx, sc[kb][r]);
            mx = fmaxf(mx, __shfl_xor(mx, 16, 64));
            mx = fmaxf(mx, __shfl_xor(mx, 32, 64));
            const float mnew  = fmaxf(fmaxf(m, mx), -1e29f);
            const float alpha = __expf(m - mnew);
            float ps = 0.f;
            #pragma unroll
            for (int kb = 0; kb < 4; kb++)
                #pragma unroll
                for (int r = 0; r < 4; r++) {
                    const float pe = __expf(sc[kb][r] - mnew);
                    sc[kb][r] = pe;
                    ps += pe;
                }
            ps += __shfl_xor(ps, 16, 64);
            ps += __shfl_xor(ps, 32, 64);
            l = l * alpha + ps;
            m = mnew;
            #pragma unroll
            for (int ob = 0; ob < 4; ob++) O[ob] *= alpha;

            #pragma unroll
            for (int kb = 0; kb < 4; kb++)
                #pragma unroll
                for (int r = 0; r < 4; r++)
                    L.at.PlT[wave][l16][kb * 16 + quad * 4 + r] = bf16_bits(sc[kb][r]);
            short8 pf[2];
            #pragma unroll
            for (int kc = 0; kc < 2; kc++)
                pf[kc] = *reinterpret_cast<const short8*>(&L.at.PlT[wave][l16][kc * 32 + quad * 8]);

            #pragma unroll
            for (int ob = 0; ob < 4; ob++)
                #pragma unroll
                for (int kc = 0; kc < 2; kc++) {
                    const int dd = ob * 16 + l16;
                    short8 vf = L.at.u.st.vts[buf][dd * 8 + ((kc * 4 + quad) ^ (dd & 7))];
                    O[ob] = __builtin_amdgcn_mfma_f32_16x16x32_bf16(vf, pf[kc], O[ob], 0, 0, 0);
                }
        }

        __syncthreads();
        #pragma unroll
        for (int ob = 0; ob < 4; ob++)
            #pragma unroll
            for (int r = 0; r < 4; r++)
                L.at.u.mg.Osh[wave][l16][ob * 16 + quad * 4 + r] = O[ob][r];
        if (quad == 0) {
            L.at.u.mg.msh[wave][l16] = m;
            L.at.u.mg.lsh[wave][l16] = l;
        }
        __syncthreads();

        #pragma unroll
        for (int part = 0; part < 8; part++) {
            const int idx = part * 256 + t;
            const int q = idx >> 6;
            const int d = idx & 63;
            const int w0 = (q >> 4), qq = q & 15;
            const float m0 = L.at.u.mg.msh[w0][qq], m1 = L.at.u.mg.msh[w0 + 2][qq];
            const float ms = fmaxf(m0, m1);
            const float x0 = __expf(m0 - ms), x1 = __expf(m1 - ms);
            const float lt = L.at.u.mg.lsh[w0][qq] * x0 + L.at.u.mg.lsh[w0 + 2][qq] * x1;
            const float oa = L.at.u.mg.Osh[w0][qq][d] * x0 + L.at.u.mg.Osh[w0 + 2][qq][d] * x1;
            out[((size_t)b * S_ + qt * 32 + q) * 64 + d] = oa / lt;
        }
    }
}

// =================== fallback 3-kernel path (verbatim round 1) ===================
__global__ __launch_bounds__(256) void prep_kernel(
    const float* __restrict__ Wq, const float* __restrict__ Wk,
    const float* __restrict__ Wv, short8* __restrict__ Wpk8,
    const void* __restrict__ mask_raw, float* __restrict__ maskf,
    float* __restrict__ maskc, short* __restrict__ cidx,
    int* __restrict__ nrounds, short* __restrict__ Khi,
    short* __restrict__ Vt)
{
    __shared__ unsigned int red[256];
    if (blockIdx.x < 96) {
        const int t = blockIdx.x * 256 + threadIdx.x;
        const int l16  = t & 15;
        const int quad = (t >> 4) & 3;
        const int nb   = (t >> 6) & 3;
        const int m    = (t >> 8) % 3;
        const int e0c  = (t >> 8) / 3;
        const float* W = (m == 0) ? Wq : ((m == 1) ? Wk : Wv);
        short8 hi, lo;
        split8(W + (size_t)(nb * 16 + l16) * E_ + e0c * 32 + quad * 8, hi, lo);
        Wpk8[(size_t)e0c * 768 + m * 256 + nb * 64 + quad * 16 + l16] = hi;
    } else {
        const unsigned int* w = (const unsigned int*)mask_raw;
        unsigned int local = 0;
        for (int i = threadIdx.x; i < 4096; i += 256) local |= w[i];
        red[threadIdx.x] = local;
        __syncthreads();
        for (int s = 128; s > 0; s >>= 1) {
            if (threadIdx.x < s) red[threadIdx.x] |= red[threadIdx.x + s];
            __syncthreads();
        }
        const unsigned int ov = red[0];
        const bool is_u8 = (ov > 1u) && ((ov >> 24) <= 1u);
        if (blockIdx.x < 160) {
            const int i = (blockIdx.x - 96) * 256 + threadIdx.x;
            int v;
            if (ov == 0u)      v = 0;
            else if (is_u8)    v = (int)((const unsigned char*)mask_raw)[i];
            else               v = (((const unsigned int*)mask_raw)[i] != 0u);
            maskf[i] = v ? -1e30f : 0.0f;
        } else {
            const int b = blockIdx.x - 160;
            int um[8];
            #pragma unroll
            for (int j = 0; j < 8; j++) {
                const int i = b * 2048 + (int)threadIdx.x * 8 + j;
                int v;
                if (ov == 0u)      v = 0;
                else if (is_u8)    v = (int)((const unsigned char*)mask_raw)[i];
                else               v = (w[i] != 0u);
                um[j] = v ? 0 : 1;
            }
            int cnt = 0;
            #pragma unroll
            for (int j = 0; j < 8; j++) cnt += um[j];
            __syncthreads();
            red[threadIdx.x] = (unsigned int)cnt;
            __syncthreads();
            for (int off = 1; off < 256; off <<= 1) {
                unsigned int a = 0;
                if ((int)threadIdx.x >= off) a = red[threadIdx.x - off];
                __syncthreads();
                red[threadIdx.x] += a;
                __syncthreads();
            }
            const int total = (int)red[255];
            int pos = (int)red[threadIdx.x] - cnt;
            #pragma unroll
            for (int j = 0; j < 8; j++) {
                const int s = (int)threadIdx.x * 8 + j;
                cidx[b * 2048 + s] = (short)(um[j] ? pos : -1);
                pos += um[j];
            }
            int nr = (total + 127) >> 7;
            if (nr == 0) nr = 1;
            if (threadIdx.x == 0) nrounds[b] = nr;
            for (int k = threadIdx.x; k < 2048; k += 256)
                maskc[b * 2048 + k] = (k < total) ? 0.0f : -1e30f;
            const int padn = (nr * 128 - total) * 64;
            for (int idx = threadIdx.x; idx < padn; idx += 256) {
                const int p = total + (idx >> 6);
                const int d = idx & 63;
                Khi[((size_t)b * 2048 + p) * 64 + d] = 0;
                Vt[((size_t)(b * 64 + d)) * VT_STRIDE + p] = 0;
            }
        }
    }
}

__global__ __launch_bounds__(512, 4) void qkv_kernel(
    const float* __restrict__ x, const short8* __restrict__ Wpk8,
    const float* __restrict__ bq, const float* __restrict__ bk,
    const float* __restrict__ bv,
    const float* __restrict__ maskf, const short* __restrict__ cidx,
    short* __restrict__ Qhi, short* __restrict__ Qlo,
    short* __restrict__ Khi, short* __restrict__ Vt)
{
    __shared__ alignas(16) float  xs[2][2][1024];
    __shared__ alignas(16) short8 wt[2][1536];
    const int tid  = threadIdx.x;
    const int wave = tid >> 6;
    const int nb   = wave & 3;
    const int rt   = wave >> 2;
    const int lane = tid & 63;
    const int l16  = lane & 15;
    const int quad = lane >> 4;
    const int row0 = blockIdx.x * 32;

    const int xr_  = (tid >> 3) & 31;
    const int xc_  = tid >> 8;
    const float* xsrc = x + (size_t)(row0 + xr_) * E_ + xc_ * 32 +
                        (((tid & 7) ^ (xr_ & 7)) * 4);
    const int xdst = xc_ * 1024 + xr_ * 32 + (tid & 7) * 4;

    floatx4 acc[3];
    #pragma unroll
    for (int m = 0; m < 3; m++) acc[m] = (floatx4){0.f,0.f,0.f,0.f};

    #pragma unroll
    for (int i = 0; i < 3; i++)
        dma16(Wpk8 + (size_t)i * 512 + tid, &wt[0][i * 512 + tid]);
    dma16(xsrc, &xs[0][0][0] + xdst);

    int buf = 0;
    for (int R = 0; R < 16; ++R) {
        __syncthreads();
        if (R + 1 < 16) {
            #pragma unroll
            for (int i = 0; i < 3; i++)
                dma16(Wpk8 + (size_t)(R + 1) * 1536 + i * 512 + tid,
                      &wt[buf ^ 1][i * 512 + tid]);
            dma16(xsrc + (R + 1) * 64, &xs[buf ^ 1][0][0] + xdst);
        }
        #pragma unroll
        for (int c = 0; c < 2; c++) {
            const int rr = rt * 16 + l16;
            const int rx = rr & 7;
            const float* xrp = &xs[buf][c][rr * 32];
            float4 a0 = *reinterpret_cast<const float4*>(xrp + (((2 * quad)     ^ rx) * 4));
            float4 a1 = *reinterpret_cast<const float4*>(xrp + (((2 * quad + 1) ^ rx) * 4));
            float av[8] = {a0.x, a0.y, a0.z, a0.w, a1.x, a1.y, a1.z, a1.w};
            short8 ah, al;
            split8v(av, ah, al);
            #pragma unroll
            for (int m = 0; m < 3; m++) {
                short8 wh = wt[buf][c * 768 + m * 256 + nb * 64 + lane];
                acc[m] = __builtin_amdgcn_mfma_f32_16x16x32_bf16(al, wh, acc[m], 0, 0, 0);
                acc[m] = __builtin_amdgcn_mfma_f32_16x16x32_bf16(ah, wh, acc[m], 0, 0, 0);
            }
        }
        buf ^= 1;
    }

    const int d = nb * 16 + l16;
    const float bqv = bq[d];
    const float bkv = bk[d];
    const float bvv = bv[d];
    const int bch = row0 >> 11;
    const int rowbase = row0 + rt * 16 + quad * 4;
    #pragma unroll
    for (int r = 0; r < 4; r++) {
        const size_t row = (size_t)(rowbase + r);
        const float q = (acc[0][r] + bqv) * 0.125f;
        const short qhv = bf16_bits(q);
        Qhi[row * 64 + d] = qhv;
        Qlo[row * 64 + d] = bf16_bits(q - bits_to_f(qhv));
        if (maskf[row] == 0.0f) {
            const int cpos = (int)cidx[row];
            Khi[((size_t)(bch << 11) + cpos) * 64 + d] = bf16_bits(acc[1][r] + bkv);
            Vt[((size_t)(bch * 64 + d)) * VT_STRIDE + cpos] = bf16_bits(acc[2][r] + bvv);
        }
    }
}

union alignas(16) AttnLds {
    struct { short8 kts[4][512]; short8 vts[4][512]; } st;
    struct {
        float Osh[4][16][65];
        float msh[4][16], lsh[4][16];
    } mg;
};

__global__ __launch_bounds__(256, 2) void attn_kernel(
    const short* __restrict__ Qhi, const short* __restrict__ Qlo,
    const short* __restrict__ Khi, const short* __restrict__ Vt,
    const float* __restrict__ maskc, const int* __restrict__ nrounds,
    float* __restrict__ out)
{
    __shared__ AttnLds lds;
    __shared__ short PlT[4][16][72];

    const int tid  = threadIdx.x;
    const int wave = tid >> 6;
    const int qsub = wave & 1;
    const int par  = wave >> 1;
    const int lane = tid & 63;
    const int l16  = lane & 15;
    const int quad = lane >> 4;
    const int b    = blockIdx.x >> 6;
    const int qt   = blockIdx.x & 63;
    const int NR   = nrounds[b];
    const size_t qbase  = (size_t)b * S_ + qt * 32 + qsub * 16;
    const size_t kplane = (size_t)b * S_;
    const short* Vb = Vt + (size_t)b * 64 * VT_STRIDE;

    short8 qh[2], ql[2];
    #pragma unroll
    for (int dc = 0; dc < 2; dc++) {
        qh[dc] = *reinterpret_cast<const short8*>(Qhi + (qbase + l16) * 64 + dc * 32 + quad * 8);
        ql[dc] = *reinterpret_cast<const short8*>(Qlo + (qbase + l16) * 64 + dc * 32 + quad * 8);
    }

    float m = -1e30f, l = 0.f;
    floatx4 O[4];
    #pragma unroll
    for (int ob = 0; ob < 4; ob++) O[ob] = (floatx4){0.f,0.f,0.f,0.f};

    #pragma unroll
    for (int p = 0; p < 2; p++) {
        #pragma unroll
        for (int i = 0; i < 2; i++) {
            const int c = i * 256 + tid;
            const int r = c >> 3, cs = c & 7;
            dma16(Khi + (kplane + p * 64 + r) * 64 + ((cs ^ (r & 7)) * 8),
                  &lds.st.kts[p][c]);
            dma16(Vb + (size_t)r * VT_STRIDE + p * 64 + ((cs ^ (r & 7)) * 8),
                  &lds.st.vts[p][c]);
        }
    }
    float4 mk4[4];
    #pragma unroll
    for (int kb = 0; kb < 4; kb++)
        mk4[kb] = *reinterpret_cast<const float4*>(
            maskc + kplane + par * 64 + kb * 16 + quad * 4);

    for (int R = 0; R < NR; ++R) {
        __syncthreads();
        const int set = R & 1;
        if (R + 1 < NR) {
            const int nset = set ^ 1;
            const int kt2 = (R + 1) * 128;
            #pragma unroll
            for (int p = 0; p < 2; p++) {
                #pragma unroll
                for (int i = 0; i < 2; i++) {
                    const int c = i * 256 + tid;
                    const int r = c >> 3, cs = c & 7;
                    dma16(Khi + (kplane + kt2 + p * 64 + r) * 64 + ((cs ^ (r & 7)) * 8),
                          &lds.st.kts[nset * 2 + p][c]);
                    dma16(Vb + (size_t)r * VT_STRIDE + kt2 + p * 64 + ((cs ^ (r & 7)) * 8),
                          &lds.st.vts[nset * 2 + p][c]);
                }
            }
        }
        const int buf = set * 2 + par;

        floatx4 sc[4];
        #pragma unroll
        for (int kb = 0; kb < 4; kb++) {
            floatx4 a = (floatx4){0.f,0.f,0.f,0.f};
            #pragma unroll
            for (int kc = 0; kc < 2; kc++) {
                const int key = kb * 16 + l16;
                short8 kf = lds.st.kts[buf][key * 8 + ((kc * 4 + quad) ^ (key & 7))];
                a = __builtin_amdgcn_mfma_f32_16x16x32_bf16(kf, qh[kc], a, 0, 0, 0);
                a = __builtin_amdgcn_mfma_f32_16x16x32_bf16(kf, ql[kc], a, 0, 0, 0);
            }
            sc[kb] = a;
        }
        #pragma unroll
        for (int kb = 0; kb < 4; kb++) {
            const float* mkp = reinterpret_cast<const float*>(&mk4[kb]);
            #pragma unroll
            for (int r = 0; r < 4; r++) sc[kb][r] += mkp[r];
        }

        if (R + 1 < NR) {
            const int ktn = (R + 1) * 128 + par * 64;
            #pragma unroll
            for (int kb = 0; kb < 4; kb++)
                mk4[kb] = *reinterpret_cast<const float4*>(
                    maskc + kplane + ktn + kb * 16 + quad * 4);
        }

        float mx = -1e30f;
        #pragma unroll
        for (int kb = 0; kb < 4; kb++)
            #pragma unroll
            for (int r = 0; r < 4; r++) mx = fmaxf(mx, sc[kb][r]);
        mx = fmaxf(mx, __shfl_xor(mx, 16, 64));
        mx = fmaxf(mx, __shfl_xor(mx, 32, 64));
        const float mnew  = fmaxf(fmaxf(m, mx), -1e29f);
        const float alpha = __expf(m - mnew);
        float ps = 0.f;
        #pragma unroll
        for (int kb = 0; kb < 4; kb++)
            #pragma unroll
            for (int r = 0; r < 4; r++) {
                const float pe = __expf(sc[kb][r] - mnew);
                sc[kb][r] = pe;
                ps += pe;
            }
        ps += __shfl_xor(ps, 16, 64);
        ps += __shfl_xor(ps, 32, 64);
        l = l * alpha + ps;
        m = mnew;
        #pragma unroll
        for (int ob = 0; ob < 4; ob++) O[ob] *= alpha;

        #pragma unroll
        for (int kb = 0; kb < 4; kb++)
            #pragma unroll
            for (int r = 0; r < 4; r++)
                PlT[wave][l16][kb * 16 + quad * 4 + r] = bf16_bits(sc[kb][r]);
        short8 pf[2];
        #pragma unroll
        for (int kc = 0; kc < 2; kc++)
            pf[kc] = *reinterpret_cast<const short8*>(&PlT[wave][l16][kc * 32 + quad * 8]);

        #pragma unroll
        for (int ob = 0; ob < 4; ob++)
            #pragma unroll
            for (int kc = 0; kc < 2; kc++) {
                const int dd = ob * 16 + l16;
                short8 vf = lds.st.vts[buf][dd * 8 + ((kc * 4 + quad) ^ (dd & 7))];
                O[ob] = __builtin_amdgcn_mfma_f32_16x16x32_bf16(vf, pf[kc], O[ob], 0, 0, 0);
            }
    }

    __syncthreads();
    #pragma unroll
    for (int ob = 0; ob < 4; ob++)
        #pragma unroll
        for (int r = 0; r < 4; r++)
            lds.mg.Osh[wave][l16][ob * 16 + quad * 4 + r] = O[ob][r];
    if (quad == 0) {
        lds.mg.msh[wave][l16] = m;
        lds.mg.lsh[wave][l16] = l;
    }
    __syncthreads();

    #pragma unroll
    for (int part = 0; part < 8; part++) {
        const int idx = part * 256 + tid;
        const int q = idx >> 6;
        const int d = idx & 63;
        const int w0 = (q >> 4), qq = q & 15;
        const float m0 = lds.mg.msh[w0][qq], m1 = lds.mg.msh[w0 + 2][qq];
        const float ms = fmaxf(m0, m1);
        const float x0 = __expf(m0 - ms), x1 = __expf(m1 - ms);
        const float lt = lds.mg.lsh[w0][qq] * x0 + lds.mg.lsh[w0 + 2][qq] * x1;
        const float oa = lds.mg.Osh[w0][qq][d] * x0 + lds.mg.Osh[w0 + 2][qq][d] * x1;
        out[((size_t)b * S_ + qt * 32 + q) * 64 + d] = oa / lt;
    }
}

extern "C" void kernel_launch(void* const* d_in, const int* in_sizes, int n_in,
                              void* d_out, int out_size, void* d_ws, size_t ws_size,
                              hipStream_t stream) {
    const float* x  = (const float*)d_in[0];
    const float* Wq = (const float*)d_in[1];
    const float* bq = (const float*)d_in[2];
    const float* Wk = (const float*)d_in[3];
    const float* bk = (const float*)d_in[4];
    const float* Wv = (const float*)d_in[5];
    const float* bv = (const float*)d_in[6];
    const void* mask = d_in[7];

    char* ws = (char*)d_ws;
    const size_t PLANE = (size_t)B_ * S_ * D_;           // 1M shorts = 2MB
    short8* Wpk8 = (short8*)ws;                           // 384 KB used (768 reserved)
    short* Qhi = (short*)(ws + 768 * 1024);
    short* Qlo = Qhi + PLANE;
    short* Khi = Qlo + PLANE;
    short* Vt  = Khi + PLANE;                             // 512*2112 shorts
    float* maskf = (float*)(Vt + (size_t)512 * VT_STRIDE);
    float* maskc = maskf + 16384;
    short* cidx  = (short*)(maskc + 16384);
    int*   nround = (int*)(cidx + 16384);
    float* outp = (float*)d_out;

    void* args[] = {
        (void*)&x, (void*)&Wq, (void*)&bq, (void*)&Wk, (void*)&bk,
        (void*)&Wv, (void*)&bv, (void*)&mask,
        (void*)&Wpk8, (void*)&Qhi, (void*)&Qlo, (void*)&Khi, (void*)&Vt,
        (void*)&maskf, (void*)&maskc, (void*)&cidx, (void*)&nround,
        (void*)&outp
    };
    hipError_t e = hipLaunchCooperativeKernel((void*)fused_kernel,
                                              dim3(512), dim3(512),
                                              args, 0, stream);
    if (e != hipSuccess) {
        // fallback: proven 3-kernel path
        prep_kernel<<<168, 256, 0, stream>>>(Wq, Wk, Wv, (short8*)Wpk8, mask,
                                             maskf, maskc, cidx, nround, Khi, Vt);
        qkv_kernel<<<512, 512, 0, stream>>>(x, (const short8*)Wpk8, bq, bk, bv,
                                            maskf, cidx, Qhi, Qlo, Khi, Vt);
        attn_kernel<<<512, 256, 0, stream>>>(Qhi, Qlo, Khi, Vt, maskc, nround,
                                             (float*)d_out);
    }
}

// Round 3
// 151.563 us; speedup vs baseline: 3.1216x; 3.1216x over previous
//
#include <hip/hip_runtime.h>
#include <hip/hip_bf16.h>

#define B_ 8
#define S_ 2048
#define E_ 1024
#define D_ 64
#define VT_STRIDE 2112   // 2048 + 64: breaks 4KB channel camping

typedef short short8 __attribute__((ext_vector_type(8)));
typedef short short4v __attribute__((ext_vector_type(4)));
typedef float floatx4 __attribute__((ext_vector_type(4)));

static __device__ __forceinline__ short bf16_bits(float f) {
    __hip_bfloat16 h = __float2bfloat16(f);
    return *reinterpret_cast<short*>(&h);
}
static __device__ __forceinline__ float bits_to_f(short s) {
    __hip_bfloat16 h = *reinterpret_cast<__hip_bfloat16*>(&s);
    return __bfloat162float(h);
}
static __device__ __forceinline__ void split8(const float* __restrict__ p,
                                              short8& hi, short8& lo) {
    #pragma unroll
    for (int j = 0; j < 8; j++) {
        float f = p[j];
        short h = bf16_bits(f);
        hi[j] = h;
        lo[j] = bf16_bits(f - bits_to_f(h));
    }
}
static __device__ __forceinline__ void split8v(const float v[8],
                                               short8& hi, short8& lo) {
    #pragma unroll
    for (int j = 0; j < 8; j++) {
        float f = v[j];
        short h = bf16_bits(f);
        hi[j] = h;
        lo[j] = bf16_bits(f - bits_to_f(h));
    }
}
static __device__ __forceinline__ void dma16(const void* src, void* lds_dst) {
    __builtin_amdgcn_global_load_lds(
        (const __attribute__((address_space(1))) unsigned int*)src,
        (__attribute__((address_space(3))) unsigned int*)lds_dst, 16, 0, 0);
}

// ---------------- prep: blocks 0..95 = W pre-pack (hi only), 96..159 = mask,
// 160..167 = per-batch key compaction (prefix scan + pad zero-fill).
// Wpk layout (short8 units): e0c*768 + m*256 + nb*64 + quad*16 + l16
__global__ __launch_bounds__(256) void prep_kernel(
    const float* __restrict__ Wq, const float* __restrict__ Wk,
    const float* __restrict__ Wv, short8* __restrict__ Wpk8,
    const void* __restrict__ mask_raw, float* __restrict__ maskf,
    float* __restrict__ maskc, short* __restrict__ cidx,
    int* __restrict__ nrounds, short* __restrict__ Khi,
    short* __restrict__ Vt)
{
    __shared__ unsigned int red[256];
    if (blockIdx.x < 96) {
        const int t = blockIdx.x * 256 + threadIdx.x;       // 24576 total
        const int l16  = t & 15;
        const int quad = (t >> 4) & 3;
        const int nb   = (t >> 6) & 3;
        const int m    = (t >> 8) % 3;
        const int e0c  = (t >> 8) / 3;                      // 0..31
        const float* W = (m == 0) ? Wq : ((m == 1) ? Wk : Wv);
        short8 hi, lo;
        split8(W + (size_t)(nb * 16 + l16) * E_ + e0c * 32 + quad * 8, hi, lo);
        Wpk8[(size_t)e0c * 768 + m * 256 + nb * 64 + quad * 16 + l16] = hi;
    } else {
        // shared format sniff (whole [B,S] buffer)
        const unsigned int* w = (const unsigned int*)mask_raw;
        unsigned int local = 0;
        for (int i = threadIdx.x; i < 4096; i += 256) local |= w[i];
        red[threadIdx.x] = local;
        __syncthreads();
        for (int s = 128; s > 0; s >>= 1) {
            if (threadIdx.x < s) red[threadIdx.x] |= red[threadIdx.x + s];
            __syncthreads();
        }
        const unsigned int ov = red[0];
        const bool is_u8 = (ov > 1u) && ((ov >> 24) <= 1u);
        if (blockIdx.x < 160) {
            const int i = (blockIdx.x - 96) * 256 + threadIdx.x;  // 64 blocks
            int v;
            if (ov == 0u)      v = 0;
            else if (is_u8)    v = (int)((const unsigned char*)mask_raw)[i];
            else               v = (((const unsigned int*)mask_raw)[i] != 0u);
            maskf[i] = v ? -1e30f : 0.0f;
        } else {
            // one block per batch: stable compaction scan of unmasked keys
            const int b = blockIdx.x - 160;
            int um[8];
            #pragma unroll
            for (int j = 0; j < 8; j++) {
                const int i = b * 2048 + (int)threadIdx.x * 8 + j;
                int v;
                if (ov == 0u)      v = 0;
                else if (is_u8)    v = (int)((const unsigned char*)mask_raw)[i];
                else               v = (w[i] != 0u);
                um[j] = v ? 0 : 1;                      // 1 = keep (unmasked)
            }
            int cnt = 0;
            #pragma unroll
            for (int j = 0; j < 8; j++) cnt += um[j];
            __syncthreads();                            // done reading red[0]
            red[threadIdx.x] = (unsigned int)cnt;
            __syncthreads();
            for (int off = 1; off < 256; off <<= 1) {   // inclusive scan
                unsigned int a = 0;
                if ((int)threadIdx.x >= off) a = red[threadIdx.x - off];
                __syncthreads();
                red[threadIdx.x] += a;
                __syncthreads();
            }
            const int total = (int)red[255];            // nk for this batch
            int pos = (int)red[threadIdx.x] - cnt;      // exclusive base
            #pragma unroll
            for (int j = 0; j < 8; j++) {
                const int s = (int)threadIdx.x * 8 + j;
                cidx[b * 2048 + s] = (short)(um[j] ? pos : -1);
                pos += um[j];
            }
            int nr = (total + 127) >> 7;
            if (nr == 0) nr = 1;
            if (threadIdx.x == 0) nrounds[b] = nr;
            for (int k = threadIdx.x; k < 2048; k += 256)
                maskc[b * 2048 + k] = (k < total) ? 0.0f : -1e30f;
            // zero pad rows [total, nr*128) of compacted K / V planes
            const int nkpad = nr * 128;
            const int padn = (nkpad - total) * 64;
            for (int idx = threadIdx.x; idx < padn; idx += 256) {
                const int p = total + (idx >> 6);
                const int d = idx & 63;
                Khi[((size_t)b * 2048 + p) * 64 + d] = 0;
                Vt[((size_t)(b * 64 + d)) * VT_STRIDE + p] = 0;
            }
        }
    }
}

// ---------------- QKV: 32 rows/block, 512 thr (8 waves = 4 nb x 2 rt),
// grid 512. W single-bf16 (hi), x hi/lo-exact. TWO e0c per barrier round
// (16 rounds). K/V rows scattered to compacted key positions.
__global__ __launch_bounds__(512, 4) void qkv_kernel(
    const float* __restrict__ x, const short8* __restrict__ Wpk8,
    const float* __restrict__ bq, const float* __restrict__ bk,
    const float* __restrict__ bv,
    const float* __restrict__ maskf, const short* __restrict__ cidx,
    short* __restrict__ Qhi, short* __restrict__ Qlo,
    short* __restrict__ Khi, short* __restrict__ Vt)
{
    __shared__ alignas(16) float  xs[2][2][1024];   // [buf][c][row*32+col] 16KB
    __shared__ alignas(16) short8 wt[2][1536];      // [buf][c*768+m*256+nb*64+lane] 48KB
    const int tid  = threadIdx.x;
    const int wave = tid >> 6;
    const int nb   = wave & 3;
    const int rt   = wave >> 2;
    const int lane = tid & 63;
    const int l16  = lane & 15;
    const int quad = lane >> 4;
    const int row0 = blockIdx.x * 32;

    const int xr_  = (tid >> 3) & 31;
    const int xc_  = tid >> 8;
    const float* xsrc = x + (size_t)(row0 + xr_) * E_ + xc_ * 32 +
                        (((tid & 7) ^ (xr_ & 7)) * 4);
    const int xdst = xc_ * 1024 + xr_ * 32 + (tid & 7) * 4;

    floatx4 acc[3];
    #pragma unroll
    for (int m = 0; m < 3; m++) acc[m] = (floatx4){0.f,0.f,0.f,0.f};

    #pragma unroll
    for (int i = 0; i < 3; i++)
        dma16(Wpk8 + (size_t)i * 512 + tid, &wt[0][i * 512 + tid]);
    dma16(xsrc, &xs[0][0][0] + xdst);

    int buf = 0;
    for (int R = 0; R < 16; ++R) {
        __syncthreads();   // drains this round's DMA
        if (R + 1 < 16) {
            #pragma unroll
            for (int i = 0; i < 3; i++)
                dma16(Wpk8 + (size_t)(R + 1) * 1536 + i * 512 + tid,
                      &wt[buf ^ 1][i * 512 + tid]);
            dma16(xsrc + (R + 1) * 64, &xs[buf ^ 1][0][0] + xdst);
        }

        #pragma unroll
        for (int c = 0; c < 2; c++) {
            const int rr = rt * 16 + l16;
            const int rx = rr & 7;
            const float* xrp = &xs[buf][c][rr * 32];
            float4 a0 = *reinterpret_cast<const float4*>(xrp + (((2 * quad)     ^ rx) * 4));
            float4 a1 = *reinterpret_cast<const float4*>(xrp + (((2 * quad + 1) ^ rx) * 4));
            float av[8] = {a0.x, a0.y, a0.z, a0.w, a1.x, a1.y, a1.z, a1.w};
            short8 ah, al;
            split8v(av, ah, al);
            #pragma unroll
            for (int m = 0; m < 3; m++) {
                short8 wh = wt[buf][c * 768 + m * 256 + nb * 64 + lane];
                acc[m] = __builtin_amdgcn_mfma_f32_16x16x32_bf16(al, wh, acc[m], 0, 0, 0);
                acc[m] = __builtin_amdgcn_mfma_f32_16x16x32_bf16(ah, wh, acc[m], 0, 0, 0);
            }
        }
        buf ^= 1;
    }

    const int d = nb * 16 + l16;
    const float bqv = bq[d];
    const float bkv = bk[d];
    const float bvv = bv[d];
    const int bch = row0 >> 11;
    const int rowbase = row0 + rt * 16 + quad * 4;
    #pragma unroll
    for (int r = 0; r < 4; r++) {
        const size_t row = (size_t)(rowbase + r);
        const float q = (acc[0][r] + bqv) * 0.125f;
        const short qhv = bf16_bits(q);
        Qhi[row * 64 + d] = qhv;
        Qlo[row * 64 + d] = bf16_bits(q - bits_to_f(qhv));
        if (maskf[row] == 0.0f) {   // unmasked key -> compacted scatter
            const int cpos = (int)cidx[row];
            Khi[((size_t)(bch << 11) + cpos) * 64 + d] = bf16_bits(acc[1][r] + bkv);
            Vt[((size_t)(bch * 64 + d)) * VT_STRIDE + cpos] = bf16_bits(acc[2][r] + bvv);
        }
    }
}

// ---------------- Flash attention over COMPACTED keys: 32 q/block,
// grid 512, pair-staged K/V tiles, key-parity waves, in-block LSE merge.
// Round count per block = nrounds[batch] (~8.5 avg instead of 16).
union alignas(16) AttnLds {
    struct { short8 kts[4][512]; short8 vts[4][512]; } st;  // 64KB
    struct {
        float Osh[4][16][65];
        float msh[4][16], lsh[4][16];
    } mg;
};

__global__ __launch_bounds__(256, 2) void attn_kernel(
    const short* __restrict__ Qhi, const short* __restrict__ Qlo,
    const short* __restrict__ Khi, const short* __restrict__ Vt,
    const float* __restrict__ maskc, const int* __restrict__ nrounds,
    float* __restrict__ out)
{
    __shared__ AttnLds lds;
    __shared__ short PlT[4][16][72];

    const int tid  = threadIdx.x;
    const int wave = tid >> 6;
    const int qsub = wave & 1;
    const int par  = wave >> 1;
    const int lane = tid & 63;
    const int l16  = lane & 15;
    const int quad = lane >> 4;
    const int b    = blockIdx.x >> 6;
    const int qt   = blockIdx.x & 63;
    const int NR   = nrounds[b];
    const size_t qbase  = (size_t)b * S_ + qt * 32 + qsub * 16;
    const size_t kplane = (size_t)b * S_;
    const short* Vb = Vt + (size_t)b * 64 * VT_STRIDE;

    short8 qh[2], ql[2];
    #pragma unroll
    for (int dc = 0; dc < 2; dc++) {
        qh[dc] = *reinterpret_cast<const short8*>(Qhi + (qbase + l16) * 64 + dc * 32 + quad * 8);
        ql[dc] = *reinterpret_cast<const short8*>(Qlo + (qbase + l16) * 64 + dc * 32 + quad * 8);
    }

    float m = -1e30f, l = 0.f;
    floatx4 O[4];
    #pragma unroll
    for (int ob = 0; ob < 4; ob++) O[ob] = (floatx4){0.f,0.f,0.f,0.f};

    #pragma unroll
    for (int p = 0; p < 2; p++) {
        #pragma unroll
        for (int i = 0; i < 2; i++) {
            const int c = i * 256 + tid;
            const int r = c >> 3, cs = c & 7;
            dma16(Khi + (kplane + p * 64 + r) * 64 + ((cs ^ (r & 7)) * 8),
                  &lds.st.kts[p][c]);
            dma16(Vb + (size_t)r * VT_STRIDE + p * 64 + ((cs ^ (r & 7)) * 8),
                  &lds.st.vts[p][c]);
        }
    }
    float4 mk4[4];
    #pragma unroll
    for (int kb = 0; kb < 4; kb++)
        mk4[kb] = *reinterpret_cast<const float4*>(
            maskc + kplane + par * 64 + kb * 16 + quad * 4);

    for (int R = 0; R < NR; ++R) {
        __syncthreads();
        const int set = R & 1;
        if (R + 1 < NR) {
            const int nset = set ^ 1;
            const int kt2 = (R + 1) * 128;
            #pragma unroll
            for (int p = 0; p < 2; p++) {
                #pragma unroll
                for (int i = 0; i < 2; i++) {
                    const int c = i * 256 + tid;
                    const int r = c >> 3, cs = c & 7;
                    dma16(Khi + (kplane + kt2 + p * 64 + r) * 64 + ((cs ^ (r & 7)) * 8),
                          &lds.st.kts[nset * 2 + p][c]);
                    dma16(Vb + (size_t)r * VT_STRIDE + kt2 + p * 64 + ((cs ^ (r & 7)) * 8),
                          &lds.st.vts[nset * 2 + p][c]);
                }
            }
        }
        const int buf = set * 2 + par;

        floatx4 sc[4];
        #pragma unroll
        for (int kb = 0; kb < 4; kb++) {
            floatx4 a = (floatx4){0.f,0.f,0.f,0.f};
            #pragma unroll
            for (int kc = 0; kc < 2; kc++) {
                const int key = kb * 16 + l16;
                short8 kf = lds.st.kts[buf][key * 8 + ((kc * 4 + quad) ^ (key & 7))];
                a = __builtin_amdgcn_mfma_f32_16x16x32_bf16(kf, qh[kc], a, 0, 0, 0);
                a = __builtin_amdgcn_mfma_f32_16x16x32_bf16(kf, ql[kc], a, 0, 0, 0);
            }
            sc[kb] = a;
        }
        #pragma unroll
        for (int kb = 0; kb < 4; kb++) {
            const float* mkp = reinterpret_cast<const float*>(&mk4[kb]);
            #pragma unroll
            for (int r = 0; r < 4; r++) sc[kb][r] += mkp[r];
        }

        if (R + 1 < NR) {
            const int ktn = (R + 1) * 128 + par * 64;
            #pragma unroll
            for (int kb = 0; kb < 4; kb++)
                mk4[kb] = *reinterpret_cast<const float4*>(
                    maskc + kplane + ktn + kb * 16 + quad * 4);
        }

        float mx = -1e30f;
        #pragma unroll
        for (int kb = 0; kb < 4; kb++)
            #pragma unroll
            for (int r = 0; r < 4; r++) mx = fmaxf(mx, sc[kb][r]);
        mx = fmaxf(mx, __shfl_xor(mx, 16, 64));
        mx = fmaxf(mx, __shfl_xor(mx, 32, 64));
        const float mnew  = fmaxf(fmaxf(m, mx), -1e29f);
        const float alpha = __expf(m - mnew);
        float ps = 0.f;
        #pragma unroll
        for (int kb = 0; kb < 4; kb++)
            #pragma unroll
            for (int r = 0; r < 4; r++) {
                const float pe = __expf(sc[kb][r] - mnew);
                sc[kb][r] = pe;
                ps += pe;
            }
        ps += __shfl_xor(ps, 16, 64);
        ps += __shfl_xor(ps, 32, 64);
        l = l * alpha + ps;
        m = mnew;
        #pragma unroll
        for (int ob = 0; ob < 4; ob++) O[ob] *= alpha;

        #pragma unroll
        for (int kb = 0; kb < 4; kb++)
            #pragma unroll
            for (int r = 0; r < 4; r++)
                PlT[wave][l16][kb * 16 + quad * 4 + r] = bf16_bits(sc[kb][r]);
        short8 pf[2];
        #pragma unroll
        for (int kc = 0; kc < 2; kc++)
            pf[kc] = *reinterpret_cast<const short8*>(&PlT[wave][l16][kc * 32 + quad * 8]);

        #pragma unroll
        for (int ob = 0; ob < 4; ob++)
            #pragma unroll
            for (int kc = 0; kc < 2; kc++) {
                const int dd = ob * 16 + l16;
                short8 vf = lds.st.vts[buf][dd * 8 + ((kc * 4 + quad) ^ (dd & 7))];
                O[ob] = __builtin_amdgcn_mfma_f32_16x16x32_bf16(vf, pf[kc], O[ob], 0, 0, 0);
            }
    }

    __syncthreads();
    #pragma unroll
    for (int ob = 0; ob < 4; ob++)
        #pragma unroll
        for (int r = 0; r < 4; r++)
            lds.mg.Osh[wave][l16][ob * 16 + quad * 4 + r] = O[ob][r];
    if (quad == 0) {
        lds.mg.msh[wave][l16] = m;
        lds.mg.lsh[wave][l16] = l;
    }
    __syncthreads();

    #pragma unroll
    for (int part = 0; part < 8; part++) {
        const int idx = part * 256 + tid;
        const int q = idx >> 6;
        const int d = idx & 63;
        const int w0 = (q >> 4), qq = q & 15;
        const float m0 = lds.mg.msh[w0][qq], m1 = lds.mg.msh[w0 + 2][qq];
        const float ms = fmaxf(m0, m1);
        const float x0 = __expf(m0 - ms), x1 = __expf(m1 - ms);
        const float lt = lds.mg.lsh[w0][qq] * x0 + lds.mg.lsh[w0 + 2][qq] * x1;
        const float oa = lds.mg.Osh[w0][qq][d] * x0 + lds.mg.Osh[w0 + 2][qq][d] * x1;
        out[((size_t)b * S_ + qt * 32 + q) * 64 + d] = oa / lt;
    }
}

extern "C" void kernel_launch(void* const* d_in, const int* in_sizes, int n_in,
                              void* d_out, int out_size, void* d_ws, size_t ws_size,
                              hipStream_t stream) {
    const float* x  = (const float*)d_in[0];
    const float* Wq = (const float*)d_in[1];
    const float* bq = (const float*)d_in[2];
    const float* Wk = (const float*)d_in[3];
    const float* bk = (const float*)d_in[4];
    const float* Wv = (const float*)d_in[5];
    const float* bv = (const float*)d_in[6];
    const void* mask = d_in[7];

    char* ws = (char*)d_ws;
    const size_t PLANE = (size_t)B_ * S_ * D_;           // 1M shorts = 2MB
    short* Wpk = (short*)ws;                              // 384 KB used (768 reserved)
    short* Qhi = (short*)(ws + 768 * 1024);
    short* Qlo = Qhi + PLANE;
    short* Khi = Qlo + PLANE;
    short* Vt  = Khi + PLANE;                             // 512*2112 shorts
    float* maskf = (float*)(Vt + (size_t)512 * VT_STRIDE);
    float* maskc = maskf + 16384;
    short* cidx  = (short*)(maskc + 16384);
    int*   nround = (int*)(cidx + 16384);

    prep_kernel<<<168, 256, 0, stream>>>(Wq, Wk, Wv, (short8*)Wpk, mask, maskf,
                                         maskc, cidx, nround, Khi, Vt);
    qkv_kernel<<<512, 512, 0, stream>>>(x, (const short8*)Wpk, bq, bk, bv,
                                        maskf, cidx, Qhi, Qlo, Khi, Vt);
    attn_kernel<<<512, 256, 0, stream>>>(Qhi, Qlo, Khi, Vt, maskc, nround,
                                         (float*)d_out);
}